// Round 10
// baseline (236.730 us; speedup 1.0000x reference)
//
#include <hip/hip_runtime.h>

#define D_MODEL 1024
#define NUM_HEADS 16
#define DK 64
#define BATCH 4
#define SEQ 2048
#define MTOT (BATCH*SEQ)

typedef __attribute__((ext_vector_type(8))) short short8;
typedef __attribute__((ext_vector_type(4))) float f32x4;
typedef __attribute__((ext_vector_type(4))) unsigned int u32x4;

__device__ __forceinline__ unsigned short f2bf(float f) {
    union { float f; unsigned u; } v; v.f = f;
    unsigned r = v.u + 0x7FFFu + ((v.u >> 16) & 1u);
    return (unsigned short)(r >> 16);
}

// packed fp32x2 -> bf16x2 (RNE), single instruction
__device__ __forceinline__ unsigned cvtpk(float lo, float hi) {
    unsigned r;
    asm("v_cvt_pk_bf16_f32 %0, %1, %2" : "=v"(r) : "v"(lo), "v"(hi));
    return r;
}

// async global->LDS, 16B per lane, linear dest (base + lane*16)
__device__ __forceinline__ void gload16(const unsigned short* g, unsigned short* l) {
    __builtin_amdgcn_global_load_lds(
        (const __attribute__((address_space(1))) unsigned int*)g,
        (__attribute__((address_space(3))) unsigned int*)l, 16, 0, 0);
}

// ---------- 4 weight transposes in one launch: W fp32 [K][N] -> WT bf16 [N][K] ----------
__global__ __launch_bounds__(256) void mha_wtrans4(
    const float* __restrict__ W0, const float* __restrict__ W1,
    const float* __restrict__ W2, const float* __restrict__ W3,
    unsigned short* __restrict__ T0, unsigned short* __restrict__ T1,
    unsigned short* __restrict__ T2, unsigned short* __restrict__ T3) {
    __shared__ float tile[64][65];
    int z = blockIdx.z;
    const float* W = z == 0 ? W0 : z == 1 ? W1 : z == 2 ? W2 : W3;
    unsigned short* WT = z == 0 ? T0 : z == 1 ? T1 : z == 2 ? T2 : T3;
    int n0 = blockIdx.x * 64, k0 = blockIdx.y * 64;
    int tx = threadIdx.x & 63, ty = threadIdx.x >> 6;
#pragma unroll
    for (int i = 0; i < 16; ++i)
        tile[ty + i * 4][tx] = W[(size_t)(k0 + ty + i * 4) * D_MODEL + n0 + tx];
    __syncthreads();
#pragma unroll
    for (int i = 0; i < 16; ++i)
        WT[(size_t)(n0 + ty + i * 4) * D_MODEL + k0 + tx] = f2bf(tile[tx][ty + i * 4]);
}

// ---------- fp32 -> bf16 elementwise ----------
__global__ __launch_bounds__(256) void mha_cvt(const float* __restrict__ in,
                                               unsigned short* __restrict__ out) {
    int i = blockIdx.x * 256 + threadIdx.x;
    float4 v = reinterpret_cast<const float4*>(in)[i];
    ushort4 o;
    o.x = f2bf(v.x); o.y = f2bf(v.y); o.z = f2bf(v.z); o.w = f2bf(v.w);
    reinterpret_cast<ushort4*>(out)[i] = o;
}

// ---------- shared GEMM pieces: 128x128 tile, BK=64, gload16, single-buffer ----------
__device__ __forceinline__ void gemm_stage(const unsigned short* Ag, const unsigned short* Bg,
                                           unsigned short* Al, unsigned short* Bl,
                                           int wid, int rsub, int c8, int kk,
                                           int brow, int bcol) {
#pragma unroll
    for (int q = 0; q < 4; ++q) {
        int i = wid * 4 + q;
        int row = i * 8 + rsub;                    // 0..127
        int gcol = kk + ((c8 ^ (row & 7)) << 3);   // pre-swizzled source
        gload16(Ag + (size_t)(brow + row) * D_MODEL + gcol, Al + i * 512);
        gload16(Bg + (size_t)(bcol + row) * D_MODEL + gcol, Bl + i * 512);
    }
}

__device__ __forceinline__ void gemm_compute(const unsigned short* Al, const unsigned short* Bl,
                                             f32x4 (&acc)[4][4],
                                             int wr, int wc, int l15, int lg, int l7) {
    short8 af[4][2], bf[4][2];
#pragma unroll
    for (int mi = 0; mi < 4; ++mi)
#pragma unroll
        for (int ks = 0; ks < 2; ++ks)
            af[mi][ks] = *reinterpret_cast<const short8*>(
                &Al[(wr * 64 + mi * 16 + l15) * 64 + (((ks * 4 + lg) ^ l7) << 3)]);
#pragma unroll
    for (int ni = 0; ni < 4; ++ni)
#pragma unroll
        for (int ks = 0; ks < 2; ++ks)
            bf[ni][ks] = *reinterpret_cast<const short8*>(
                &Bl[(wc * 64 + ni * 16 + l15) * 64 + (((ks * 4 + lg) ^ l7) << 3)]);
#pragma unroll
    for (int mi = 0; mi < 4; ++mi)
#pragma unroll
        for (int ni = 0; ni < 4; ++ni)
#pragma unroll
            for (int ks = 0; ks < 2; ++ks)
                acc[mi][ni] = __builtin_amdgcn_mfma_f32_16x16x32_bf16(
                    af[mi][ks], bf[ni][ks], acc[mi][ni], 0, 0, 0);
}

// ---------- projection GEMM: bf16 A via gload16, single-buffer ----------
// MODE 0: bf16 out = (acc+bias)*scale.  MODE 2: V -> VT[bh][d][s] transpose epilogue.
template <int MODE>
__global__ __launch_bounds__(256) void mha_gemm_proj(
    const unsigned short* __restrict__ A, const unsigned short* __restrict__ WT,
    const float* __restrict__ bias,
    unsigned short* __restrict__ outb, unsigned short* __restrict__ VT, float scale) {
    __shared__ unsigned short SM[MODE == 2 ? 17408 : 16384];
    unsigned short* Al = SM;
    unsigned short* Bl = SM + 8192;

    int wid = threadIdx.x >> 6;
    int lane = threadIdx.x & 63;
    int wr = wid >> 1, wc = wid & 1;
    int brow = blockIdx.x * 128;
    int bcol = blockIdx.y * 128;
    int l15 = lane & 15, lg = lane >> 4;
    int c8 = lane & 7, rsub = lane >> 3;
    int l7 = l15 & 7;

    f32x4 acc[4][4] = {};
    for (int kk = 0; kk < D_MODEL; kk += 64) {
        __syncthreads();
        gemm_stage(A, WT, Al, Bl, wid, rsub, c8, kk, brow, bcol);
        __syncthreads();
        gemm_compute(Al, Bl, acc, wr, wc, l15, lg, l7);
    }

    if (MODE == 0) {
#pragma unroll
        for (int ni = 0; ni < 4; ++ni) {
            int col = bcol + wc * 64 + ni * 16 + l15;
            float bv2 = bias[col];
#pragma unroll
            for (int mi = 0; mi < 4; ++mi)
#pragma unroll
                for (int j = 0; j < 4; ++j) {
                    int row = brow + wr * 64 + mi * 16 + lg * 4 + j;
                    outb[(size_t)row * D_MODEL + col] = f2bf((acc[mi][ni][j] + bv2) * scale);
                }
        }
    } else {
        // V: transpose in LDS, write VT[bh][d][s] coalesced
        __syncthreads();  // all waves out of K-loop before SM reuse
        unsigned short* T = SM;  // 128 x 136 = 17408 shorts
#pragma unroll
        for (int ni = 0; ni < 4; ++ni) {
            int c = wc * 64 + ni * 16 + l15;
            float bv2 = bias[bcol + c];
#pragma unroll
            for (int mi = 0; mi < 4; ++mi)
#pragma unroll
                for (int j = 0; j < 4; ++j) {
                    int r = wr * 64 + mi * 16 + lg * 4 + j;
                    T[c * 136 + r] = f2bf(acc[mi][ni][j] + bv2);
                }
        }
        __syncthreads();
        int c = threadIdx.x >> 1;
        int rh = (threadIdx.x & 1) * 64;
        int gcol = bcol + c;
        int h = gcol >> 6, d = gcol & 63;
        int b = brow >> 11, s0 = brow & (SEQ - 1);
        unsigned short* dst = VT + ((size_t)((b * 16 + h) * 64 + d)) * SEQ + s0 + rh;
        const unsigned short* src = &T[c * 136 + rh];
#pragma unroll
        for (int i = 0; i < 8; ++i)
            *reinterpret_cast<short8*>(dst + i * 8) =
                *reinterpret_cast<const short8*>(src + i * 8);
    }
}

// ---------- output projection: fp32 out = acc + bias + residual ----------
__global__ __launch_bounds__(256) void mha_gemm_o(const unsigned short* __restrict__ A,
                                                  const unsigned short* __restrict__ WT,
                                                  const float* __restrict__ bias,
                                                  const float* __restrict__ residual,
                                                  float* __restrict__ outf) {
    __shared__ unsigned short SM[16384];
    unsigned short* Al = SM;
    unsigned short* Bl = SM + 8192;

    int wid = threadIdx.x >> 6;
    int lane = threadIdx.x & 63;
    int wr = wid >> 1, wc = wid & 1;
    int brow = blockIdx.x * 128;
    int bcol = blockIdx.y * 128;
    int l15 = lane & 15, lg = lane >> 4;
    int c8 = lane & 7, rsub = lane >> 3;
    int l7 = l15 & 7;

    f32x4 acc[4][4] = {};
    for (int kk = 0; kk < D_MODEL; kk += 64) {
        __syncthreads();
        gemm_stage(A, WT, Al, Bl, wid, rsub, c8, kk, brow, bcol);
        __syncthreads();
        gemm_compute(Al, Bl, acc, wr, wc, l15, lg, l7);
    }
#pragma unroll
    for (int ni = 0; ni < 4; ++ni) {
        int col = bcol + wc * 64 + ni * 16 + l15;
        float bv2 = bias[col];
#pragma unroll
        for (int mi = 0; mi < 4; ++mi)
#pragma unroll
            for (int j = 0; j < 4; ++j) {
                int row = brow + wr * 64 + mi * 16 + lg * 4 + j;
                outf[(size_t)row * D_MODEL + col] =
                    acc[mi][ni][j] + bv2 + residual[(size_t)row * D_MODEL + col];
            }
    }
}

// ---------- one 64-kv attention tile, M=4 (64 q-rows/wave), P in registers ----------
__device__ __forceinline__ void attn_tile4(const unsigned short* Kd,
                                           const unsigned short* Vd,
                                           const short8 (&aq)[4][2],
                                           f32x4 (&acc)[4][4],
                                           float (&lsum)[4],
                                           int l15, int lg, int l7) {
    f32x4 z[4][4];
#pragma unroll
    for (int t = 0; t < 4; ++t) {
        int krow = (t * 16 + l15) * 64;
        short8 kf0 = *reinterpret_cast<const short8*>(&Kd[krow + ((lg ^ l7) << 3)]);
        short8 kf1 = *reinterpret_cast<const short8*>(&Kd[krow + (((4 + lg) ^ l7) << 3)]);
#pragma unroll
        for (int m = 0; m < 4; ++m) {
            f32x4 zz = {};
            zz = __builtin_amdgcn_mfma_f32_16x16x32_bf16(kf0, aq[m][0], zz, 0, 0, 0);
            zz = __builtin_amdgcn_mfma_f32_16x16x32_bf16(kf1, aq[m][1], zz, 0, 0, 0);
            z[m][t] = zz;
        }
    }
#pragma unroll
    for (int m = 0; m < 4; ++m)
#pragma unroll
        for (int t = 0; t < 4; ++t)
#pragma unroll
            for (int j = 0; j < 4; ++j) {
                float p = __builtin_amdgcn_exp2f(z[m][t][j]);
                z[m][t][j] = p;
                lsum[m] += p;
            }
    short8 pf[4][2];
#pragma unroll
    for (int m = 0; m < 4; ++m)
#pragma unroll
        for (int ks = 0; ks < 2; ++ks) {
            union { u32x4 u; short8 s; } cv;
            cv.u = (u32x4){cvtpk(z[m][2 * ks][0], z[m][2 * ks][1]),
                           cvtpk(z[m][2 * ks][2], z[m][2 * ks][3]),
                           cvtpk(z[m][2 * ks + 1][0], z[m][2 * ks + 1][1]),
                           cvtpk(z[m][2 * ks + 1][2], z[m][2 * ks + 1][3])};
            pf[m][ks] = cv.s;
        }
#pragma unroll
    for (int dt = 0; dt < 4; ++dt) {
        int vrow = (dt * 16 + l15) * 64;
        short8 vf0 = *reinterpret_cast<const short8*>(&Vd[vrow + ((lg ^ l7) << 3)]);
        short8 vf1 = *reinterpret_cast<const short8*>(&Vd[vrow + (((4 + lg) ^ l7) << 3)]);
#pragma unroll
        for (int m = 0; m < 4; ++m) {
            acc[m][dt] = __builtin_amdgcn_mfma_f32_16x16x32_bf16(vf0, pf[m][0], acc[m][dt], 0, 0, 0);
            acc[m][dt] = __builtin_amdgcn_mfma_f32_16x16x32_bf16(vf1, pf[m][1], acc[m][dt], 0, 0, 0);
        }
    }
}

// ---------- flash attention: 4 waves/block, 256 q-rows/block, 2-phase dbuf K/V ----------
__global__ __launch_bounds__(256) void mha_attn(const unsigned short* __restrict__ Q,
                                                const unsigned short* __restrict__ K,
                                                const unsigned short* __restrict__ VT,
                                                unsigned short* __restrict__ ctx) {
    __shared__ unsigned short K0[64 * 64], V0[64 * 64];
    __shared__ unsigned short K1[64 * 64], V1[64 * 64];

    int lane = threadIdx.x & 63;
    int w = threadIdx.x >> 6;
    int l15 = lane & 15, lg = lane >> 4;
    int l7 = l15 & 7;
    int c8 = lane & 7, rsub = lane >> 3;

    // XCD-chunked remap: 512 blocks, 64/XCD -> 8 heads per XCD (K/V L2-resident)
    int id = blockIdx.x;
    int nid = (id & 7) * 64 + (id >> 3);
    int bx = nid & 7;
    int bh = nid >> 3;
    int b = bh >> 4, h = bh & 15;
    int q0 = bx * 256 + w * 64;

    short8 aq[4][2];
    {
        const unsigned short* Qp = Q + (size_t)(b * SEQ + q0) * D_MODEL + h * DK;
#pragma unroll
        for (int m = 0; m < 4; ++m)
#pragma unroll
            for (int ks = 0; ks < 2; ++ks)
                aq[m][ks] = *reinterpret_cast<const short8*>(
                    Qp + (size_t)(m * 16 + l15) * D_MODEL + ks * 32 + lg * 8);
    }

    f32x4 acc[4][4] = {};
    float lsum[4] = {};

    const unsigned short* Kbh = K + (size_t)(b * SEQ) * D_MODEL + h * DK;
    const unsigned short* VTbh = VT + (size_t)bh * DK * SEQ;

    int i0 = w * 2, i1 = w * 2 + 1;
    int row0 = i0 * 8 + rsub, row1 = i1 * 8 + rsub;  // physical LDS rows
    int sw0 = (c8 ^ (row0 & 7)) << 3, sw1 = (c8 ^ (row1 & 7)) << 3;
    // sigma: physical row -> logical K row, bits [t1 t0|lg1 lg0|j1 j0] -> [t1 lg1 lg0 t0 j1 j0]
    int sr0 = (row0 & 32) | ((row0 & 12) << 1) | ((row0 & 16) >> 2) | (row0 & 3);
    int sr1 = (row1 & 32) | ((row1 & 12) << 1) | ((row1 & 16) >> 2) | (row1 & 3);

#define STAGE(Kd, Vd, kb)                                                        \
    do {                                                                         \
        gload16(Kbh + (size_t)((kb) + sr0) * D_MODEL + sw0, (Kd) + i0 * 512);    \
        gload16(Kbh + (size_t)((kb) + sr1) * D_MODEL + sw1, (Kd) + i1 * 512);    \
        gload16(VTbh + (size_t)row0 * SEQ + (kb) + sw0, (Vd) + i0 * 512);        \
        gload16(VTbh + (size_t)row1 * SEQ + (kb) + sw1, (Vd) + i1 * 512);        \
    } while (0)

    STAGE(K0, V0, 0);
    __syncthreads();

    for (int kb = 0; kb < SEQ; kb += 128) {
        STAGE(K1, V1, kb + 64);
        attn_tile4(K0, V0, aq, acc, lsum, l15, lg, l7);
        __syncthreads();
        if (kb + 128 < SEQ) STAGE(K0, V0, kb + 128);
        attn_tile4(K1, V1, aq, acc, lsum, l15, lg, l7);
        __syncthreads();
    }
#undef STAGE

#pragma unroll
    for (int m = 0; m < 4; ++m) {
        float l = lsum[m];
        l += __shfl_xor(l, 16);
        l += __shfl_xor(l, 32);
        float rl = 1.0f / l;
        int q = q0 + m * 16 + l15;
        unsigned short* cp = ctx + (size_t)(b * SEQ + q) * D_MODEL + h * DK + lg * 4;
#pragma unroll
        for (int dt = 0; dt < 4; ++dt) {
            ushort4 o;
            o.x = f2bf(acc[m][dt][0] * rl);
            o.y = f2bf(acc[m][dt][1] * rl);
            o.z = f2bf(acc[m][dt][2] * rl);
            o.w = f2bf(acc[m][dt][3] * rl);
            *reinterpret_cast<ushort4*>(cp + dt * 16) = o;
        }
    }
}

// ---------- LayerNorm over rows of 1024 fp32 ----------
__global__ __launch_bounds__(256) void mha_ln(const float* __restrict__ X,
                                              const float* __restrict__ gamma,
                                              const float* __restrict__ beta,
                                              float* __restrict__ out) {
    int row = blockIdx.x;
    int t = threadIdx.x;
    const float* x = X + (size_t)row * D_MODEL;
    float4 v = reinterpret_cast<const float4*>(x)[t];
    float s = v.x + v.y + v.z + v.w;
    float s2 = v.x * v.x + v.y * v.y + v.z * v.z + v.w * v.w;
#pragma unroll
    for (int off = 1; off < 64; off <<= 1) {
        s += __shfl_xor(s, off);
        s2 += __shfl_xor(s2, off);
    }
    __shared__ float ws[8];
    int wid = t >> 6;
    if ((t & 63) == 0) { ws[wid] = s; ws[4 + wid] = s2; }
    __syncthreads();
    s = ws[0] + ws[1] + ws[2] + ws[3];
    s2 = ws[4] + ws[5] + ws[6] + ws[7];
    float mu = s * (1.f / D_MODEL);
    float var = s2 * (1.f / D_MODEL) - mu * mu;
    float rstd = rsqrtf(var + 1e-5f);
    float4 gv = reinterpret_cast<const float4*>(gamma)[t];
    float4 bv = reinterpret_cast<const float4*>(beta)[t];
    float4 o;
    o.x = (v.x - mu) * rstd * gv.x + bv.x;
    o.y = (v.y - mu) * rstd * gv.y + bv.y;
    o.z = (v.z - mu) * rstd * gv.z + bv.z;
    o.w = (v.w - mu) * rstd * gv.w + bv.w;
    reinterpret_cast<float4*>(out + (size_t)row * D_MODEL)[t] = o;
}

extern "C" void kernel_launch(void* const* d_in, const int* in_sizes, int n_in,
                              void* d_out, int out_size, void* d_ws, size_t ws_size,
                              hipStream_t stream) {
    const float* query = (const float*)d_in[0];
    const float* key   = (const float*)d_in[1];
    const float* value = (const float*)d_in[2];
    const float* Wq = (const float*)d_in[3];
    const float* bq = (const float*)d_in[4];
    const float* Wk = (const float*)d_in[5];
    const float* bk = (const float*)d_in[6];
    const float* Wv = (const float*)d_in[7];
    const float* bv = (const float*)d_in[8];
    const float* Wo = (const float*)d_in[9];
    const float* bo = (const float*)d_in[10];
    const float* gamma = (const float*)d_in[11];
    const float* beta  = (const float*)d_in[12];

    char* ws = (char*)d_ws;
    const size_t MB = 1u << 20;
    unsigned short* WTq = (unsigned short*)(ws + 0 * MB);
    unsigned short* WTk = (unsigned short*)(ws + 2 * MB);
    unsigned short* WTv = (unsigned short*)(ws + 4 * MB);
    unsigned short* WTo = (unsigned short*)(ws + 6 * MB);
    unsigned short* Ab  = (unsigned short*)(ws + 8 * MB);   // shared A buffer, 16.8 MB
    unsigned short* Qb  = (unsigned short*)(ws + 25 * MB);
    unsigned short* Kb  = (unsigned short*)(ws + 42 * MB);
    unsigned short* VT  = (unsigned short*)(ws + 59 * MB);
    unsigned short* ctx = (unsigned short*)(ws + 76 * MB);
    float* tmp          = (float*)(ws + 8 * MB);            // over dead Ab+Qb (33.6 MB)

    const float C1 = 0.180336880f;  // 0.125 * log2(e), folded into Q projection

    dim3 b256(256);
    dim3 ggrid(MTOT / 128, D_MODEL / 128);
    int nblk = (MTOT * D_MODEL / 4) / 256;  // 8192

    mha_wtrans4<<<dim3(16, 16, 4), b256, 0, stream>>>(Wq, Wk, Wv, Wo, WTq, WTk, WTv, WTo);

    mha_cvt<<<dim3(nblk), b256, 0, stream>>>(query, Ab);
    mha_gemm_proj<0><<<ggrid, b256, 0, stream>>>(Ab, WTq, bq, Qb, nullptr, C1);

    mha_cvt<<<dim3(nblk), b256, 0, stream>>>(key, Ab);
    mha_gemm_proj<0><<<ggrid, b256, 0, stream>>>(Ab, WTk, bk, Kb, nullptr, 1.0f);

    mha_cvt<<<dim3(nblk), b256, 0, stream>>>(value, Ab);
    mha_gemm_proj<2><<<ggrid, b256, 0, stream>>>(Ab, WTv, bv, nullptr, VT, 1.0f);

    mha_attn<<<dim3(BATCH * NUM_HEADS * SEQ / 256), b256, 0, stream>>>(Qb, Kb, VT, ctx);

    mha_gemm_o<<<ggrid, b256, 0, stream>>>(ctx, WTo, bo, query, tmp);

    mha_ln<<<dim3(MTOT), b256, 0, stream>>>(tmp, gamma, beta, (float*)d_out);
}

// Round 11
// 194.828 us; speedup vs baseline: 1.2151x; 1.2151x over previous
//
#include <hip/hip_runtime.h>

#define D_MODEL 1024
#define NUM_HEADS 16
#define DK 64
#define BATCH 4
#define SEQ 2048
#define MTOT (BATCH*SEQ)

typedef __attribute__((ext_vector_type(8))) short short8;
typedef __attribute__((ext_vector_type(4))) float f32x4;
typedef __attribute__((ext_vector_type(4))) unsigned int u32x4;

__device__ __forceinline__ unsigned short f2bf(float f) {
    union { float f; unsigned u; } v; v.f = f;
    unsigned r = v.u + 0x7FFFu + ((v.u >> 16) & 1u);
    return (unsigned short)(r >> 16);
}

__device__ __forceinline__ float bf2f(unsigned short u) {
    union { unsigned u; float f; } v; v.u = ((unsigned)u) << 16;
    return v.f;
}

// packed fp32x2 -> bf16x2 (RNE), single instruction
__device__ __forceinline__ unsigned cvtpk(float lo, float hi) {
    unsigned r;
    asm("v_cvt_pk_bf16_f32 %0, %1, %2" : "=v"(r) : "v"(lo), "v"(hi));
    return r;
}

// async global->LDS, 16B per lane, linear dest (base + lane*16)
__device__ __forceinline__ void gload16(const unsigned short* g, unsigned short* l) {
    __builtin_amdgcn_global_load_lds(
        (const __attribute__((address_space(1))) unsigned int*)g,
        (__attribute__((address_space(3))) unsigned int*)l, 16, 0, 0);
}

// ---------- 4 weight transposes in one launch: W fp32 [K][N] -> WT bf16 [N][K] ----------
__global__ __launch_bounds__(256) void mha_wtrans4(
    const float* __restrict__ W0, const float* __restrict__ W1,
    const float* __restrict__ W2, const float* __restrict__ W3,
    unsigned short* __restrict__ T0, unsigned short* __restrict__ T1,
    unsigned short* __restrict__ T2, unsigned short* __restrict__ T3) {
    __shared__ float tile[64][65];
    int z = blockIdx.z;
    const float* W = z == 0 ? W0 : z == 1 ? W1 : z == 2 ? W2 : W3;
    unsigned short* WT = z == 0 ? T0 : z == 1 ? T1 : z == 2 ? T2 : T3;
    int n0 = blockIdx.x * 64, k0 = blockIdx.y * 64;
    int tx = threadIdx.x & 63, ty = threadIdx.x >> 6;
#pragma unroll
    for (int i = 0; i < 16; ++i)
        tile[ty + i * 4][tx] = W[(size_t)(k0 + ty + i * 4) * D_MODEL + n0 + tx];
    __syncthreads();
#pragma unroll
    for (int i = 0; i < 16; ++i)
        WT[(size_t)(n0 + ty + i * 4) * D_MODEL + k0 + tx] = f2bf(tile[tx][ty + i * 4]);
}

// ---------- 3 fp32 -> bf16 conversions in one launch ----------
__global__ __launch_bounds__(256) void mha_cvt3(
    const float* __restrict__ i0, const float* __restrict__ i1, const float* __restrict__ i2,
    unsigned short* __restrict__ o0, unsigned short* __restrict__ o1, unsigned short* __restrict__ o2) {
    int y = blockIdx.y;
    const float* in = y == 0 ? i0 : y == 1 ? i1 : i2;
    unsigned short* out = y == 0 ? o0 : y == 1 ? o1 : o2;
    int i = blockIdx.x * 256 + threadIdx.x;
    float4 v = reinterpret_cast<const float4*>(in)[i];
    ushort4 o;
    o.x = f2bf(v.x); o.y = f2bf(v.y); o.z = f2bf(v.z); o.w = f2bf(v.w);
    reinterpret_cast<ushort4*>(out)[i] = o;
}

// ---------- shared GEMM pieces: 128x128 tile, BK=64, dbuf, global_load_lds ----------
__device__ __forceinline__ void gemm_stage(const unsigned short* Ag, const unsigned short* Bg,
                                           unsigned short* Al, unsigned short* Bl,
                                           int wid, int rsub, int c8, int kk,
                                           int brow, int bcol) {
#pragma unroll
    for (int q = 0; q < 4; ++q) {
        int i = wid * 4 + q;
        int row = i * 8 + rsub;                    // 0..127
        int gcol = kk + ((c8 ^ (row & 7)) << 3);   // pre-swizzled source
        gload16(Ag + (size_t)(brow + row) * D_MODEL + gcol, Al + i * 512);
        gload16(Bg + (size_t)(bcol + row) * D_MODEL + gcol, Bl + i * 512);
    }
}

__device__ __forceinline__ void gemm_compute(const unsigned short* Al, const unsigned short* Bl,
                                             f32x4 (&acc)[4][4],
                                             int wr, int wc, int l15, int lg, int l7) {
    short8 af[4][2], bf[4][2];
#pragma unroll
    for (int mi = 0; mi < 4; ++mi)
#pragma unroll
        for (int ks = 0; ks < 2; ++ks)
            af[mi][ks] = *reinterpret_cast<const short8*>(
                &Al[(wr * 64 + mi * 16 + l15) * 64 + (((ks * 4 + lg) ^ l7) << 3)]);
#pragma unroll
    for (int ni = 0; ni < 4; ++ni)
#pragma unroll
        for (int ks = 0; ks < 2; ++ks)
            bf[ni][ks] = *reinterpret_cast<const short8*>(
                &Bl[(wc * 64 + ni * 16 + l15) * 64 + (((ks * 4 + lg) ^ l7) << 3)]);
#pragma unroll
    for (int mi = 0; mi < 4; ++mi)
#pragma unroll
        for (int ni = 0; ni < 4; ++ni)
#pragma unroll
            for (int ks = 0; ks < 2; ++ks)
                acc[mi][ni] = __builtin_amdgcn_mfma_f32_16x16x32_bf16(
                    af[mi][ks], bf[ni][ks], acc[mi][ni], 0, 0, 0);
}

// ---------- QKV projections, one launch (z selects); V writes VT layout ----------
__global__ __launch_bounds__(256) void mha_gemm_qkv(
    const unsigned short* __restrict__ Aq, const unsigned short* __restrict__ Ak,
    const unsigned short* __restrict__ Av,
    const unsigned short* __restrict__ Wq, const unsigned short* __restrict__ Wk,
    const unsigned short* __restrict__ Wv,
    const float* __restrict__ bq, const float* __restrict__ bk, const float* __restrict__ bv,
    unsigned short* __restrict__ Qb, unsigned short* __restrict__ Kb,
    unsigned short* __restrict__ VT, float qscale) {
    __shared__ unsigned short SM[32768];  // 64 KB: A0 B0 A1 B1
    unsigned short* A0 = SM;
    unsigned short* B0 = SM + 8192;
    unsigned short* A1 = SM + 16384;
    unsigned short* B1 = SM + 24576;

    int z = blockIdx.z;
    const unsigned short* A = z == 0 ? Aq : z == 1 ? Ak : Av;
    const unsigned short* WT = z == 0 ? Wq : z == 1 ? Wk : Wv;
    const float* bias = z == 0 ? bq : z == 1 ? bk : bv;

    int wid = threadIdx.x >> 6;
    int lane = threadIdx.x & 63;
    int wr = wid >> 1, wc = wid & 1;
    int brow = blockIdx.x * 128;
    int bcol = blockIdx.y * 128;
    int l15 = lane & 15, lg = lane >> 4;
    int c8 = lane & 7, rsub = lane >> 3;
    int l7 = l15 & 7;

    f32x4 acc[4][4] = {};
    gemm_stage(A, WT, A0, B0, wid, rsub, c8, 0, brow, bcol);
    __syncthreads();
    for (int kk = 0; kk < D_MODEL; kk += 128) {
        gemm_stage(A, WT, A1, B1, wid, rsub, c8, kk + 64, brow, bcol);
        gemm_compute(A0, B0, acc, wr, wc, l15, lg, l7);
        __syncthreads();
        if (kk + 128 < D_MODEL)
            gemm_stage(A, WT, A0, B0, wid, rsub, c8, kk + 128, brow, bcol);
        gemm_compute(A1, B1, acc, wr, wc, l15, lg, l7);
        __syncthreads();
    }

    if (z < 2) {
        unsigned short* outb = z == 0 ? Qb : Kb;
        float scale = z == 0 ? qscale : 1.0f;
#pragma unroll
        for (int ni = 0; ni < 4; ++ni) {
            int col = bcol + wc * 64 + ni * 16 + l15;
            float bv2 = bias[col];
#pragma unroll
            for (int mi = 0; mi < 4; ++mi)
#pragma unroll
                for (int j = 0; j < 4; ++j) {
                    int row = brow + wr * 64 + mi * 16 + lg * 4 + j;
                    outb[(size_t)row * D_MODEL + col] = f2bf((acc[mi][ni][j] + bv2) * scale);
                }
        }
    } else {
        // V: transpose in LDS, write VT[bh][d][s] coalesced
        unsigned short* T = SM;  // 128 x 136 = 17408 shorts, fits
#pragma unroll
        for (int ni = 0; ni < 4; ++ni) {
            int c = wc * 64 + ni * 16 + l15;
            float bv2 = bias[bcol + c];
#pragma unroll
            for (int mi = 0; mi < 4; ++mi)
#pragma unroll
                for (int j = 0; j < 4; ++j) {
                    int r = wr * 64 + mi * 16 + lg * 4 + j;
                    T[c * 136 + r] = f2bf(acc[mi][ni][j] + bv2);
                }
        }
        __syncthreads();
        int c = threadIdx.x >> 1;
        int rh = (threadIdx.x & 1) * 64;
        int gcol = bcol + c;
        int h = gcol >> 6, d = gcol & 63;
        int b = brow >> 11, s0 = brow & (SEQ - 1);
        unsigned short* dst = VT + ((size_t)((b * 16 + h) * 64 + d)) * SEQ + s0 + rh;
        const unsigned short* src = &T[c * 136 + rh];
#pragma unroll
        for (int i = 0; i < 8; ++i)
            *reinterpret_cast<short8*>(dst + i * 8) =
                *reinterpret_cast<const short8*>(src + i * 8);
    }
}

// ---------- output projection: bf16 tmp = acc + bias + residual ----------
__global__ __launch_bounds__(256) void mha_gemm_o(const unsigned short* __restrict__ A,
                                                  const unsigned short* __restrict__ WT,
                                                  const float* __restrict__ bias,
                                                  const float* __restrict__ residual,
                                                  unsigned short* __restrict__ outb) {
    __shared__ unsigned short SM[32768];
    unsigned short* A0 = SM;
    unsigned short* B0 = SM + 8192;
    unsigned short* A1 = SM + 16384;
    unsigned short* B1 = SM + 24576;

    int wid = threadIdx.x >> 6;
    int lane = threadIdx.x & 63;
    int wr = wid >> 1, wc = wid & 1;
    int brow = blockIdx.x * 128;
    int bcol = blockIdx.y * 128;
    int l15 = lane & 15, lg = lane >> 4;
    int c8 = lane & 7, rsub = lane >> 3;
    int l7 = l15 & 7;

    f32x4 acc[4][4] = {};
    gemm_stage(A, WT, A0, B0, wid, rsub, c8, 0, brow, bcol);
    __syncthreads();
    for (int kk = 0; kk < D_MODEL; kk += 128) {
        gemm_stage(A, WT, A1, B1, wid, rsub, c8, kk + 64, brow, bcol);
        gemm_compute(A0, B0, acc, wr, wc, l15, lg, l7);
        __syncthreads();
        if (kk + 128 < D_MODEL)
            gemm_stage(A, WT, A0, B0, wid, rsub, c8, kk + 128, brow, bcol);
        gemm_compute(A1, B1, acc, wr, wc, l15, lg, l7);
        __syncthreads();
    }
#pragma unroll
    for (int ni = 0; ni < 4; ++ni) {
        int col = bcol + wc * 64 + ni * 16 + l15;
        float bv2 = bias[col];
#pragma unroll
        for (int mi = 0; mi < 4; ++mi)
#pragma unroll
            for (int j = 0; j < 4; ++j) {
                int row = brow + wr * 64 + mi * 16 + lg * 4 + j;
                outb[(size_t)row * D_MODEL + col] =
                    f2bf(acc[mi][ni][j] + bv2 + residual[(size_t)row * D_MODEL + col]);
            }
    }
}

// ---------- one 64-kv attention tile, P fully in-register (round-6 verbatim) ----------
__device__ __forceinline__ void attn_tile(const unsigned short* Kd,
                                          const unsigned short* Vd,
                                          const short8 aq[2][2],
                                          f32x4 (&acc)[2][4],
                                          float (&lsum)[2],
                                          int l15, int lg, int l7) {
    f32x4 z[2][4];
#pragma unroll
    for (int t = 0; t < 4; ++t) {
        int krow = (t * 16 + l15) * 64;
        short8 kf0 = *reinterpret_cast<const short8*>(&Kd[krow + ((lg ^ l7) << 3)]);
        short8 kf1 = *reinterpret_cast<const short8*>(&Kd[krow + (((4 + lg) ^ l7) << 3)]);
#pragma unroll
        for (int m = 0; m < 2; ++m) {
            f32x4 zz = {};
            zz = __builtin_amdgcn_mfma_f32_16x16x32_bf16(kf0, aq[m][0], zz, 0, 0, 0);
            zz = __builtin_amdgcn_mfma_f32_16x16x32_bf16(kf1, aq[m][1], zz, 0, 0, 0);
            z[m][t] = zz;
        }
    }
#pragma unroll
    for (int m = 0; m < 2; ++m)
#pragma unroll
        for (int t = 0; t < 4; ++t)
#pragma unroll
            for (int j = 0; j < 4; ++j) {
                float p = __builtin_amdgcn_exp2f(z[m][t][j]);
                z[m][t][j] = p;
                lsum[m] += p;
            }
    short8 pf[2][2];
#pragma unroll
    for (int m = 0; m < 2; ++m)
#pragma unroll
        for (int ks = 0; ks < 2; ++ks) {
            union { u32x4 u; short8 s; } cv;
            cv.u = (u32x4){cvtpk(z[m][2 * ks][0], z[m][2 * ks][1]),
                           cvtpk(z[m][2 * ks][2], z[m][2 * ks][3]),
                           cvtpk(z[m][2 * ks + 1][0], z[m][2 * ks + 1][1]),
                           cvtpk(z[m][2 * ks + 1][2], z[m][2 * ks + 1][3])};
            pf[m][ks] = cv.s;
        }
#pragma unroll
    for (int dt = 0; dt < 4; ++dt) {
        int vrow = (dt * 16 + l15) * 64;
        short8 vf0 = *reinterpret_cast<const short8*>(&Vd[vrow + ((lg ^ l7) << 3)]);
        short8 vf1 = *reinterpret_cast<const short8*>(&Vd[vrow + (((4 + lg) ^ l7) << 3)]);
#pragma unroll
        for (int m = 0; m < 2; ++m) {
            acc[m][dt] = __builtin_amdgcn_mfma_f32_16x16x32_bf16(vf0, pf[m][0], acc[m][dt], 0, 0, 0);
            acc[m][dt] = __builtin_amdgcn_mfma_f32_16x16x32_bf16(vf1, pf[m][1], acc[m][dt], 0, 0, 0);
        }
    }
}

// ---------- flash attention: 4 waves/block, 128 q-rows, 2-phase dbuf K/V ----------
__global__ __launch_bounds__(256, 4) void mha_attn(const unsigned short* __restrict__ Q,
                                                   const unsigned short* __restrict__ K,
                                                   const unsigned short* __restrict__ VT,
                                                   unsigned short* __restrict__ ctx) {
    __shared__ unsigned short K0[64 * 64], V0[64 * 64];
    __shared__ unsigned short K1[64 * 64], V1[64 * 64];

    int lane = threadIdx.x & 63;
    int w = threadIdx.x >> 6;
    int l15 = lane & 15, lg = lane >> 4;
    int l7 = l15 & 7;
    int c8 = lane & 7, rsub = lane >> 3;

    // XCD-chunked remap: 8 heads per XCD -> K/V L2-resident
    int id = blockIdx.x + gridDim.x * blockIdx.y;
    int nid = (id & 7) * 128 + (id >> 3);
    int bx = nid & 15;
    int bh = nid >> 4;
    int b = bh >> 4, h = bh & 15;
    int q0 = bx * 128 + w * 32;

    short8 aq[2][2];
    {
        const unsigned short* Qp = Q + (size_t)(b * SEQ + q0) * D_MODEL + h * DK;
#pragma unroll
        for (int m = 0; m < 2; ++m)
#pragma unroll
            for (int ks = 0; ks < 2; ++ks)
                aq[m][ks] = *reinterpret_cast<const short8*>(
                    Qp + (size_t)(m * 16 + l15) * D_MODEL + ks * 32 + lg * 8);
    }

    f32x4 acc[2][4] = {};
    float lsum[2] = {};

    const unsigned short* Kbh = K + (size_t)(b * SEQ) * D_MODEL + h * DK;
    const unsigned short* VTbh = VT + (size_t)bh * DK * SEQ;

    int i0 = w * 2, i1 = w * 2 + 1;
    int row0 = i0 * 8 + rsub, row1 = i1 * 8 + rsub;  // physical LDS rows
    int sw0 = (c8 ^ (row0 & 7)) << 3, sw1 = (c8 ^ (row1 & 7)) << 3;
    // sigma: physical row -> logical K row, bits [t1 t0|lg1 lg0|j1 j0] -> [t1 lg1 lg0 t0 j1 j0]
    int sr0 = (row0 & 32) | ((row0 & 12) << 1) | ((row0 & 16) >> 2) | (row0 & 3);
    int sr1 = (row1 & 32) | ((row1 & 12) << 1) | ((row1 & 16) >> 2) | (row1 & 3);

#define STAGE(Kd, Vd, kb)                                                        \
    do {                                                                         \
        gload16(Kbh + (size_t)((kb) + sr0) * D_MODEL + sw0, (Kd) + i0 * 512);    \
        gload16(Kbh + (size_t)((kb) + sr1) * D_MODEL + sw1, (Kd) + i1 * 512);    \
        gload16(VTbh + (size_t)row0 * SEQ + (kb) + sw0, (Vd) + i0 * 512);        \
        gload16(VTbh + (size_t)row1 * SEQ + (kb) + sw1, (Vd) + i1 * 512);        \
    } while (0)

    STAGE(K0, V0, 0);
    __syncthreads();

    for (int kb = 0; kb < SEQ; kb += 128) {
        STAGE(K1, V1, kb + 64);
        attn_tile(K0, V0, aq, acc, lsum, l15, lg, l7);
        __syncthreads();
        if (kb + 128 < SEQ) STAGE(K0, V0, kb + 128);
        attn_tile(K1, V1, aq, acc, lsum, l15, lg, l7);
        __syncthreads();
    }
#undef STAGE

#pragma unroll
    for (int m = 0; m < 2; ++m) {
        float l = lsum[m];
        l += __shfl_xor(l, 16);
        l += __shfl_xor(l, 32);
        float rl = 1.0f / l;
        int q = q0 + m * 16 + l15;
        unsigned short* cp = ctx + (size_t)(b * SEQ + q) * D_MODEL + h * DK + lg * 4;
#pragma unroll
        for (int dt = 0; dt < 4; ++dt) {
            ushort4 o;
            o.x = f2bf(acc[m][dt][0] * rl);
            o.y = f2bf(acc[m][dt][1] * rl);
            o.z = f2bf(acc[m][dt][2] * rl);
            o.w = f2bf(acc[m][dt][3] * rl);
            *reinterpret_cast<ushort4*>(cp + dt * 16) = o;
        }
    }
}

// ---------- LayerNorm over rows of 1024, bf16 input, fp32 output ----------
__global__ __launch_bounds__(256) void mha_ln(const unsigned short* __restrict__ X,
                                              const float* __restrict__ gamma,
                                              const float* __restrict__ beta,
                                              float* __restrict__ out) {
    int row = blockIdx.x;
    int t = threadIdx.x;
    const unsigned short* x = X + (size_t)row * D_MODEL;
    ushort4 u = reinterpret_cast<const ushort4*>(x)[t];
    float v0 = bf2f(u.x), v1 = bf2f(u.y), v2 = bf2f(u.z), v3 = bf2f(u.w);
    float s = v0 + v1 + v2 + v3;
    float s2 = v0 * v0 + v1 * v1 + v2 * v2 + v3 * v3;
#pragma unroll
    for (int off = 1; off < 64; off <<= 1) {
        s += __shfl_xor(s, off);
        s2 += __shfl_xor(s2, off);
    }
    __shared__ float ws[8];
    int wid = t >> 6;
    if ((t & 63) == 0) { ws[wid] = s; ws[4 + wid] = s2; }
    __syncthreads();
    s = ws[0] + ws[1] + ws[2] + ws[3];
    s2 = ws[4] + ws[5] + ws[6] + ws[7];
    float mu = s * (1.f / D_MODEL);
    float var = s2 * (1.f / D_MODEL) - mu * mu;
    float rstd = rsqrtf(var + 1e-5f);
    float4 gv = reinterpret_cast<const float4*>(gamma)[t];
    float4 bv = reinterpret_cast<const float4*>(beta)[t];
    float4 o;
    o.x = (v0 - mu) * rstd * gv.x + bv.x;
    o.y = (v1 - mu) * rstd * gv.y + bv.y;
    o.z = (v2 - mu) * rstd * gv.z + bv.z;
    o.w = (v3 - mu) * rstd * gv.w + bv.w;
    reinterpret_cast<float4*>(out + (size_t)row * D_MODEL)[t] = o;
}

extern "C" void kernel_launch(void* const* d_in, const int* in_sizes, int n_in,
                              void* d_out, int out_size, void* d_ws, size_t ws_size,
                              hipStream_t stream) {
    const float* query = (const float*)d_in[0];
    const float* key   = (const float*)d_in[1];
    const float* value = (const float*)d_in[2];
    const float* Wq = (const float*)d_in[3];
    const float* bq = (const float*)d_in[4];
    const float* Wk = (const float*)d_in[5];
    const float* bk = (const float*)d_in[6];
    const float* Wv = (const float*)d_in[7];
    const float* bv = (const float*)d_in[8];
    const float* Wo = (const float*)d_in[9];
    const float* bo = (const float*)d_in[10];
    const float* gamma = (const float*)d_in[11];
    const float* beta  = (const float*)d_in[12];

    char* ws = (char*)d_ws;
    const size_t MB = 1u << 20;
    // each activation buffer = 8192*1024*2 B = 16 MiB exactly
    unsigned short* WTq = (unsigned short*)(ws + 0 * MB);
    unsigned short* WTk = (unsigned short*)(ws + 2 * MB);
    unsigned short* WTv = (unsigned short*)(ws + 4 * MB);
    unsigned short* WTo = (unsigned short*)(ws + 6 * MB);
    unsigned short* Aq  = (unsigned short*)(ws + 8 * MB);
    unsigned short* Ak  = (unsigned short*)(ws + 24 * MB);
    unsigned short* Av  = (unsigned short*)(ws + 40 * MB);
    unsigned short* Qb  = (unsigned short*)(ws + 56 * MB);
    unsigned short* Kb  = (unsigned short*)(ws + 72 * MB);
    unsigned short* VT  = (unsigned short*)(ws + 88 * MB);  // ends at 104 MiB
    unsigned short* ctx = (unsigned short*)(ws + 8 * MB);   // over Aq (dead after qkv)
    unsigned short* tmp = (unsigned short*)(ws + 24 * MB);  // over Ak (dead), bf16

    const float C1 = 0.180336880f;  // 0.125 * log2(e), folded into Q projection

    dim3 b256(256);
    mha_wtrans4<<<dim3(16, 16, 4), b256, 0, stream>>>(Wq, Wk, Wv, Wo, WTq, WTk, WTv, WTo);

    int nblk = (MTOT * D_MODEL / 4) / 256;  // 8192
    mha_cvt3<<<dim3(nblk, 3), b256, 0, stream>>>(query, key, value, Aq, Ak, Av);

    mha_gemm_qkv<<<dim3(MTOT / 128, D_MODEL / 128, 3), b256, 0, stream>>>(
        Aq, Ak, Av, WTq, WTk, WTv, bq, bk, bv, Qb, Kb, VT, C1);

    mha_attn<<<dim3(SEQ / 128, BATCH * NUM_HEADS), b256, 0, stream>>>(Qb, Kb, VT, ctx);

    mha_gemm_o<<<dim3(MTOT / 128, D_MODEL / 128), b256, 0, stream>>>(ctx, WTo, bo, query, tmp);

    mha_ln<<<dim3(MTOT), b256, 0, stream>>>(tmp, gamma, beta, (float*)d_out);
}

// Round 12
// 194.021 us; speedup vs baseline: 1.2201x; 1.0042x over previous
//
#include <hip/hip_runtime.h>

#define D_MODEL 1024
#define NUM_HEADS 16
#define DK 64
#define BATCH 4
#define SEQ 2048
#define MTOT (BATCH*SEQ)

typedef __attribute__((ext_vector_type(8))) short short8;
typedef __attribute__((ext_vector_type(4))) float f32x4;
typedef __attribute__((ext_vector_type(4))) unsigned int u32x4;

__device__ __forceinline__ unsigned short f2bf(float f) {
    union { float f; unsigned u; } v; v.f = f;
    unsigned r = v.u + 0x7FFFu + ((v.u >> 16) & 1u);
    return (unsigned short)(r >> 16);
}

__device__ __forceinline__ float bf2f(unsigned short u) {
    union { unsigned u; float f; } v; v.u = ((unsigned)u) << 16;
    return v.f;
}

// packed fp32x2 -> bf16x2 (RNE), single instruction
__device__ __forceinline__ unsigned cvtpk(float lo, float hi) {
    unsigned r;
    asm("v_cvt_pk_bf16_f32 %0, %1, %2" : "=v"(r) : "v"(lo), "v"(hi));
    return r;
}

// async global->LDS, 16B per lane, linear dest (base + lane*16)
__device__ __forceinline__ void gload16(const unsigned short* g, unsigned short* l) {
    __builtin_amdgcn_global_load_lds(
        (const __attribute__((address_space(1))) unsigned int*)g,
        (__attribute__((address_space(3))) unsigned int*)l, 16, 0, 0);
}

// ---------- 4 weight transposes in one launch: W fp32 [K][N] -> WT bf16 [N][K] ----------
__global__ __launch_bounds__(256) void mha_wtrans4(
    const float* __restrict__ W0, const float* __restrict__ W1,
    const float* __restrict__ W2, const float* __restrict__ W3,
    unsigned short* __restrict__ T0, unsigned short* __restrict__ T1,
    unsigned short* __restrict__ T2, unsigned short* __restrict__ T3) {
    __shared__ float tile[64][65];
    int z = blockIdx.z;
    const float* W = z == 0 ? W0 : z == 1 ? W1 : z == 2 ? W2 : W3;
    unsigned short* WT = z == 0 ? T0 : z == 1 ? T1 : z == 2 ? T2 : T3;
    int n0 = blockIdx.x * 64, k0 = blockIdx.y * 64;
    int tx = threadIdx.x & 63, ty = threadIdx.x >> 6;
#pragma unroll
    for (int i = 0; i < 16; ++i)
        tile[ty + i * 4][tx] = W[(size_t)(k0 + ty + i * 4) * D_MODEL + n0 + tx];
    __syncthreads();
#pragma unroll
    for (int i = 0; i < 16; ++i)
        WT[(size_t)(n0 + ty + i * 4) * D_MODEL + k0 + tx] = f2bf(tile[tx][ty + i * 4]);
}

// ---------- 3 fp32 -> bf16 conversions in one launch ----------
__global__ __launch_bounds__(256) void mha_cvt3(
    const float* __restrict__ i0, const float* __restrict__ i1, const float* __restrict__ i2,
    unsigned short* __restrict__ o0, unsigned short* __restrict__ o1, unsigned short* __restrict__ o2) {
    int y = blockIdx.y;
    const float* in = y == 0 ? i0 : y == 1 ? i1 : i2;
    unsigned short* out = y == 0 ? o0 : y == 1 ? o1 : o2;
    int i = blockIdx.x * 256 + threadIdx.x;
    float4 v = reinterpret_cast<const float4*>(in)[i];
    ushort4 o;
    o.x = f2bf(v.x); o.y = f2bf(v.y); o.z = f2bf(v.z); o.w = f2bf(v.w);
    reinterpret_cast<ushort4*>(out)[i] = o;
}

// ---------- shared GEMM pieces: 128x128 tile, BK=64, dbuf, global_load_lds ----------
__device__ __forceinline__ void gemm_stage(const unsigned short* Ag, const unsigned short* Bg,
                                           unsigned short* Al, unsigned short* Bl,
                                           int wid, int rsub, int c8, int kk,
                                           int brow, int bcol) {
#pragma unroll
    for (int q = 0; q < 4; ++q) {
        int i = wid * 4 + q;
        int row = i * 8 + rsub;                    // 0..127
        int gcol = kk + ((c8 ^ (row & 7)) << 3);   // pre-swizzled source
        gload16(Ag + (size_t)(brow + row) * D_MODEL + gcol, Al + i * 512);
        gload16(Bg + (size_t)(bcol + row) * D_MODEL + gcol, Bl + i * 512);
    }
}

__device__ __forceinline__ void gemm_compute(const unsigned short* Al, const unsigned short* Bl,
                                             f32x4 (&acc)[4][4],
                                             int wr, int wc, int l15, int lg, int l7) {
    short8 af[4][2], bf[4][2];
#pragma unroll
    for (int mi = 0; mi < 4; ++mi)
#pragma unroll
        for (int ks = 0; ks < 2; ++ks)
            af[mi][ks] = *reinterpret_cast<const short8*>(
                &Al[(wr * 64 + mi * 16 + l15) * 64 + (((ks * 4 + lg) ^ l7) << 3)]);
#pragma unroll
    for (int ni = 0; ni < 4; ++ni)
#pragma unroll
        for (int ks = 0; ks < 2; ++ks)
            bf[ni][ks] = *reinterpret_cast<const short8*>(
                &Bl[(wc * 64 + ni * 16 + l15) * 64 + (((ks * 4 + lg) ^ l7) << 3)]);
#pragma unroll
    for (int mi = 0; mi < 4; ++mi)
#pragma unroll
        for (int ni = 0; ni < 4; ++ni)
#pragma unroll
            for (int ks = 0; ks < 2; ++ks)
                acc[mi][ni] = __builtin_amdgcn_mfma_f32_16x16x32_bf16(
                    af[mi][ks], bf[ni][ks], acc[mi][ni], 0, 0, 0);
}

// ---------- QKV projections, one launch (z selects); V writes VT layout ----------
__global__ __launch_bounds__(256) void mha_gemm_qkv(
    const unsigned short* __restrict__ Aq, const unsigned short* __restrict__ Ak,
    const unsigned short* __restrict__ Av,
    const unsigned short* __restrict__ Wq, const unsigned short* __restrict__ Wk,
    const unsigned short* __restrict__ Wv,
    const float* __restrict__ bq, const float* __restrict__ bk, const float* __restrict__ bv,
    unsigned short* __restrict__ Qb, unsigned short* __restrict__ Kb,
    unsigned short* __restrict__ VT, float qscale) {
    __shared__ unsigned short SM[32768];  // 64 KB: A0 B0 A1 B1
    unsigned short* A0 = SM;
    unsigned short* B0 = SM + 8192;
    unsigned short* A1 = SM + 16384;
    unsigned short* B1 = SM + 24576;

    int z = blockIdx.z;
    const unsigned short* A = z == 0 ? Aq : z == 1 ? Ak : Av;
    const unsigned short* WT = z == 0 ? Wq : z == 1 ? Wk : Wv;
    const float* bias = z == 0 ? bq : z == 1 ? bk : bv;

    int wid = threadIdx.x >> 6;
    int lane = threadIdx.x & 63;
    int wr = wid >> 1, wc = wid & 1;
    int brow = blockIdx.x * 128;
    int bcol = blockIdx.y * 128;
    int l15 = lane & 15, lg = lane >> 4;
    int c8 = lane & 7, rsub = lane >> 3;
    int l7 = l15 & 7;

    f32x4 acc[4][4] = {};
    gemm_stage(A, WT, A0, B0, wid, rsub, c8, 0, brow, bcol);
    __syncthreads();
    for (int kk = 0; kk < D_MODEL; kk += 128) {
        gemm_stage(A, WT, A1, B1, wid, rsub, c8, kk + 64, brow, bcol);
        gemm_compute(A0, B0, acc, wr, wc, l15, lg, l7);
        __syncthreads();
        if (kk + 128 < D_MODEL)
            gemm_stage(A, WT, A0, B0, wid, rsub, c8, kk + 128, brow, bcol);
        gemm_compute(A1, B1, acc, wr, wc, l15, lg, l7);
        __syncthreads();
    }

    if (z < 2) {
        unsigned short* outb = z == 0 ? Qb : Kb;
        float scale = z == 0 ? qscale : 1.0f;
#pragma unroll
        for (int ni = 0; ni < 4; ++ni) {
            int col = bcol + wc * 64 + ni * 16 + l15;
            float bv2 = bias[col];
#pragma unroll
            for (int mi = 0; mi < 4; ++mi)
#pragma unroll
                for (int j = 0; j < 4; ++j) {
                    int row = brow + wr * 64 + mi * 16 + lg * 4 + j;
                    outb[(size_t)row * D_MODEL + col] = f2bf((acc[mi][ni][j] + bv2) * scale);
                }
        }
    } else {
        // V: transpose in LDS, write VT[bh][d][s] coalesced
        unsigned short* T = SM;  // 128 x 136 = 17408 shorts, fits
#pragma unroll
        for (int ni = 0; ni < 4; ++ni) {
            int c = wc * 64 + ni * 16 + l15;
            float bv2 = bias[bcol + c];
#pragma unroll
            for (int mi = 0; mi < 4; ++mi)
#pragma unroll
                for (int j = 0; j < 4; ++j) {
                    int r = wr * 64 + mi * 16 + lg * 4 + j;
                    T[c * 136 + r] = f2bf(acc[mi][ni][j] + bv2);
                }
        }
        __syncthreads();
        int c = threadIdx.x >> 1;
        int rh = (threadIdx.x & 1) * 64;
        int gcol = bcol + c;
        int h = gcol >> 6, d = gcol & 63;
        int b = brow >> 11, s0 = brow & (SEQ - 1);
        unsigned short* dst = VT + ((size_t)((b * 16 + h) * 64 + d)) * SEQ + s0 + rh;
        const unsigned short* src = &T[c * 136 + rh];
#pragma unroll
        for (int i = 0; i < 8; ++i)
            *reinterpret_cast<short8*>(dst + i * 8) =
                *reinterpret_cast<const short8*>(src + i * 8);
    }
}

// ---------- output projection: bf16 tmp = acc + bias + residual(bf16) ----------
__global__ __launch_bounds__(256) void mha_gemm_o(const unsigned short* __restrict__ A,
                                                  const unsigned short* __restrict__ WT,
                                                  const float* __restrict__ bias,
                                                  const unsigned short* __restrict__ residual,
                                                  unsigned short* __restrict__ outb) {
    __shared__ unsigned short SM[32768];
    unsigned short* A0 = SM;
    unsigned short* B0 = SM + 8192;
    unsigned short* A1 = SM + 16384;
    unsigned short* B1 = SM + 24576;

    int wid = threadIdx.x >> 6;
    int lane = threadIdx.x & 63;
    int wr = wid >> 1, wc = wid & 1;
    int brow = blockIdx.x * 128;
    int bcol = blockIdx.y * 128;
    int l15 = lane & 15, lg = lane >> 4;
    int c8 = lane & 7, rsub = lane >> 3;
    int l7 = l15 & 7;

    f32x4 acc[4][4] = {};
    gemm_stage(A, WT, A0, B0, wid, rsub, c8, 0, brow, bcol);
    __syncthreads();
    for (int kk = 0; kk < D_MODEL; kk += 128) {
        gemm_stage(A, WT, A1, B1, wid, rsub, c8, kk + 64, brow, bcol);
        gemm_compute(A0, B0, acc, wr, wc, l15, lg, l7);
        __syncthreads();
        if (kk + 128 < D_MODEL)
            gemm_stage(A, WT, A0, B0, wid, rsub, c8, kk + 128, brow, bcol);
        gemm_compute(A1, B1, acc, wr, wc, l15, lg, l7);
        __syncthreads();
    }
#pragma unroll
    for (int ni = 0; ni < 4; ++ni) {
        int col = bcol + wc * 64 + ni * 16 + l15;
        float bv2 = bias[col];
#pragma unroll
        for (int mi = 0; mi < 4; ++mi)
#pragma unroll
            for (int j = 0; j < 4; ++j) {
                int row = brow + wr * 64 + mi * 16 + lg * 4 + j;
                outb[(size_t)row * D_MODEL + col] =
                    f2bf(acc[mi][ni][j] + bv2 +
                         bf2f(residual[(size_t)row * D_MODEL + col]));
            }
    }
}

// ---------- one 64-kv attention tile, P fully in-register (round-6 verbatim) ----------
__device__ __forceinline__ void attn_tile(const unsigned short* Kd,
                                          const unsigned short* Vd,
                                          const short8 aq[2][2],
                                          f32x4 (&acc)[2][4],
                                          float (&lsum)[2],
                                          int l15, int lg, int l7) {
    f32x4 z[2][4];
#pragma unroll
    for (int t = 0; t < 4; ++t) {
        int krow = (t * 16 + l15) * 64;
        short8 kf0 = *reinterpret_cast<const short8*>(&Kd[krow + ((lg ^ l7) << 3)]);
        short8 kf1 = *reinterpret_cast<const short8*>(&Kd[krow + (((4 + lg) ^ l7) << 3)]);
#pragma unroll
        for (int m = 0; m < 2; ++m) {
            f32x4 zz = {};
            zz = __builtin_amdgcn_mfma_f32_16x16x32_bf16(kf0, aq[m][0], zz, 0, 0, 0);
            zz = __builtin_amdgcn_mfma_f32_16x16x32_bf16(kf1, aq[m][1], zz, 0, 0, 0);
            z[m][t] = zz;
        }
    }
#pragma unroll
    for (int m = 0; m < 2; ++m)
#pragma unroll
        for (int t = 0; t < 4; ++t)
#pragma unroll
            for (int j = 0; j < 4; ++j) {
                float p = __builtin_amdgcn_exp2f(z[m][t][j]);
                z[m][t][j] = p;
                lsum[m] += p;
            }
    short8 pf[2][2];
#pragma unroll
    for (int m = 0; m < 2; ++m)
#pragma unroll
        for (int ks = 0; ks < 2; ++ks) {
            union { u32x4 u; short8 s; } cv;
            cv.u = (u32x4){cvtpk(z[m][2 * ks][0], z[m][2 * ks][1]),
                           cvtpk(z[m][2 * ks][2], z[m][2 * ks][3]),
                           cvtpk(z[m][2 * ks + 1][0], z[m][2 * ks + 1][1]),
                           cvtpk(z[m][2 * ks + 1][2], z[m][2 * ks + 1][3])};
            pf[m][ks] = cv.s;
        }
#pragma unroll
    for (int dt = 0; dt < 4; ++dt) {
        int vrow = (dt * 16 + l15) * 64;
        short8 vf0 = *reinterpret_cast<const short8*>(&Vd[vrow + ((lg ^ l7) << 3)]);
        short8 vf1 = *reinterpret_cast<const short8*>(&Vd[vrow + (((4 + lg) ^ l7) << 3)]);
#pragma unroll
        for (int m = 0; m < 2; ++m) {
            acc[m][dt] = __builtin_amdgcn_mfma_f32_16x16x32_bf16(vf0, pf[m][0], acc[m][dt], 0, 0, 0);
            acc[m][dt] = __builtin_amdgcn_mfma_f32_16x16x32_bf16(vf1, pf[m][1], acc[m][dt], 0, 0, 0);
        }
    }
}

// ---------- flash attention: 4 waves/block, 128 q-rows, 2-phase dbuf K/V ----------
__global__ __launch_bounds__(256, 4) void mha_attn(const unsigned short* __restrict__ Q,
                                                   const unsigned short* __restrict__ K,
                                                   const unsigned short* __restrict__ VT,
                                                   unsigned short* __restrict__ ctx) {
    __shared__ unsigned short K0[64 * 64], V0[64 * 64];
    __shared__ unsigned short K1[64 * 64], V1[64 * 64];

    int lane = threadIdx.x & 63;
    int w = threadIdx.x >> 6;
    int l15 = lane & 15, lg = lane >> 4;
    int l7 = l15 & 7;
    int c8 = lane & 7, rsub = lane >> 3;

    // XCD-chunked remap: 8 heads per XCD -> K/V L2-resident
    int id = blockIdx.x + gridDim.x * blockIdx.y;
    int nid = (id & 7) * 128 + (id >> 3);
    int bx = nid & 15;
    int bh = nid >> 4;
    int b = bh >> 4, h = bh & 15;
    int q0 = bx * 128 + w * 32;

    short8 aq[2][2];
    {
        const unsigned short* Qp = Q + (size_t)(b * SEQ + q0) * D_MODEL + h * DK;
#pragma unroll
        for (int m = 0; m < 2; ++m)
#pragma unroll
            for (int ks = 0; ks < 2; ++ks)
                aq[m][ks] = *reinterpret_cast<const short8*>(
                    Qp + (size_t)(m * 16 + l15) * D_MODEL + ks * 32 + lg * 8);
    }

    f32x4 acc[2][4] = {};
    float lsum[2] = {};

    const unsigned short* Kbh = K + (size_t)(b * SEQ) * D_MODEL + h * DK;
    const unsigned short* VTbh = VT + (size_t)bh * DK * SEQ;

    int i0 = w * 2, i1 = w * 2 + 1;
    int row0 = i0 * 8 + rsub, row1 = i1 * 8 + rsub;  // physical LDS rows
    int sw0 = (c8 ^ (row0 & 7)) << 3, sw1 = (c8 ^ (row1 & 7)) << 3;
    // sigma: physical row -> logical K row, bits [t1 t0|lg1 lg0|j1 j0] -> [t1 lg1 lg0 t0 j1 j0]
    int sr0 = (row0 & 32) | ((row0 & 12) << 1) | ((row0 & 16) >> 2) | (row0 & 3);
    int sr1 = (row1 & 32) | ((row1 & 12) << 1) | ((row1 & 16) >> 2) | (row1 & 3);

#define STAGE(Kd, Vd, kb)                                                        \
    do {                                                                         \
        gload16(Kbh + (size_t)((kb) + sr0) * D_MODEL + sw0, (Kd) + i0 * 512);    \
        gload16(Kbh + (size_t)((kb) + sr1) * D_MODEL + sw1, (Kd) + i1 * 512);    \
        gload16(VTbh + (size_t)row0 * SEQ + (kb) + sw0, (Vd) + i0 * 512);        \
        gload16(VTbh + (size_t)row1 * SEQ + (kb) + sw1, (Vd) + i1 * 512);        \
    } while (0)

    STAGE(K0, V0, 0);
    __syncthreads();

    for (int kb = 0; kb < SEQ; kb += 128) {
        STAGE(K1, V1, kb + 64);
        attn_tile(K0, V0, aq, acc, lsum, l15, lg, l7);
        __syncthreads();
        if (kb + 128 < SEQ) STAGE(K0, V0, kb + 128);
        attn_tile(K1, V1, aq, acc, lsum, l15, lg, l7);
        __syncthreads();
    }
#undef STAGE

#pragma unroll
    for (int m = 0; m < 2; ++m) {
        float l = lsum[m];
        l += __shfl_xor(l, 16);
        l += __shfl_xor(l, 32);
        float rl = 1.0f / l;
        int q = q0 + m * 16 + l15;
        unsigned short* cp = ctx + (size_t)(b * SEQ + q) * D_MODEL + h * DK + lg * 4;
#pragma unroll
        for (int dt = 0; dt < 4; ++dt) {
            ushort4 o;
            o.x = f2bf(acc[m][dt][0] * rl);
            o.y = f2bf(acc[m][dt][1] * rl);
            o.z = f2bf(acc[m][dt][2] * rl);
            o.w = f2bf(acc[m][dt][3] * rl);
            *reinterpret_cast<ushort4*>(cp + dt * 16) = o;
        }
    }
}

// ---------- LayerNorm over rows of 1024, bf16 input, fp32 output ----------
__global__ __launch_bounds__(256) void mha_ln(const unsigned short* __restrict__ X,
                                              const float* __restrict__ gamma,
                                              const float* __restrict__ beta,
                                              float* __restrict__ out) {
    int row = blockIdx.x;
    int t = threadIdx.x;
    const unsigned short* x = X + (size_t)row * D_MODEL;
    ushort4 u = reinterpret_cast<const ushort4*>(x)[t];
    float v0 = bf2f(u.x), v1 = bf2f(u.y), v2 = bf2f(u.z), v3 = bf2f(u.w);
    float s = v0 + v1 + v2 + v3;
    float s2 = v0 * v0 + v1 * v1 + v2 * v2 + v3 * v3;
#pragma unroll
    for (int off = 1; off < 64; off <<= 1) {
        s += __shfl_xor(s, off);
        s2 += __shfl_xor(s2, off);
    }
    __shared__ float ws[8];
    int wid = t >> 6;
    if ((t & 63) == 0) { ws[wid] = s; ws[4 + wid] = s2; }
    __syncthreads();
    s = ws[0] + ws[1] + ws[2] + ws[3];
    s2 = ws[4] + ws[5] + ws[6] + ws[7];
    float mu = s * (1.f / D_MODEL);
    float var = s2 * (1.f / D_MODEL) - mu * mu;
    float rstd = rsqrtf(var + 1e-5f);
    float4 gv = reinterpret_cast<const float4*>(gamma)[t];
    float4 bv = reinterpret_cast<const float4*>(beta)[t];
    float4 o;
    o.x = (v0 - mu) * rstd * gv.x + bv.x;
    o.y = (v1 - mu) * rstd * gv.y + bv.y;
    o.z = (v2 - mu) * rstd * gv.z + bv.z;
    o.w = (v3 - mu) * rstd * gv.w + bv.w;
    reinterpret_cast<float4*>(out + (size_t)row * D_MODEL)[t] = o;
}

extern "C" void kernel_launch(void* const* d_in, const int* in_sizes, int n_in,
                              void* d_out, int out_size, void* d_ws, size_t ws_size,
                              hipStream_t stream) {
    const float* query = (const float*)d_in[0];
    const float* key   = (const float*)d_in[1];
    const float* value = (const float*)d_in[2];
    const float* Wq = (const float*)d_in[3];
    const float* bq = (const float*)d_in[4];
    const float* Wk = (const float*)d_in[5];
    const float* bk = (const float*)d_in[6];
    const float* Wv = (const float*)d_in[7];
    const float* bv = (const float*)d_in[8];
    const float* Wo = (const float*)d_in[9];
    const float* bo = (const float*)d_in[10];
    const float* gamma = (const float*)d_in[11];
    const float* beta  = (const float*)d_in[12];

    char* ws = (char*)d_ws;
    const size_t MB = 1u << 20;
    // each activation buffer = 8192*1024*2 B = 16 MiB exactly
    unsigned short* WTq = (unsigned short*)(ws + 0 * MB);
    unsigned short* WTk = (unsigned short*)(ws + 2 * MB);
    unsigned short* WTv = (unsigned short*)(ws + 4 * MB);
    unsigned short* WTo = (unsigned short*)(ws + 6 * MB);
    unsigned short* Aq  = (unsigned short*)(ws + 8 * MB);   // stays live: residual for gemm_o
    unsigned short* Ak  = (unsigned short*)(ws + 24 * MB);
    unsigned short* Av  = (unsigned short*)(ws + 40 * MB);
    unsigned short* Qb  = (unsigned short*)(ws + 56 * MB);
    unsigned short* Kb  = (unsigned short*)(ws + 72 * MB);
    unsigned short* VT  = (unsigned short*)(ws + 88 * MB);  // ends at 104 MiB
    unsigned short* ctx = (unsigned short*)(ws + 40 * MB);  // over Av (dead after qkv)
    unsigned short* tmp = (unsigned short*)(ws + 24 * MB);  // over Ak (dead), bf16

    const float C1 = 0.180336880f;  // 0.125 * log2(e), folded into Q projection

    dim3 b256(256);
    mha_wtrans4<<<dim3(16, 16, 4), b256, 0, stream>>>(Wq, Wk, Wv, Wo, WTq, WTk, WTv, WTo);

    int nblk = (MTOT * D_MODEL / 4) / 256;  // 8192
    mha_cvt3<<<dim3(nblk, 3), b256, 0, stream>>>(query, key, value, Aq, Ak, Av);

    mha_gemm_qkv<<<dim3(MTOT / 128, D_MODEL / 128, 3), b256, 0, stream>>>(
        Aq, Ak, Av, WTq, WTk, WTv, bq, bk, bv, Qb, Kb, VT, C1);

    mha_attn<<<dim3(SEQ / 128, BATCH * NUM_HEADS), b256, 0, stream>>>(Qb, Kb, VT, ctx);

    mha_gemm_o<<<dim3(MTOT / 128, D_MODEL / 128), b256, 0, stream>>>(ctx, WTo, bo, Aq, tmp);

    mha_ln<<<dim3(MTOT), b256, 0, stream>>>(tmp, gamma, beta, (float*)d_out);
}